// Round 2
// baseline (2383.354 us; speedup 1.0000x reference)
//
#include <hip/hip_runtime.h>
#include <math.h>

#define NN 100000
#define NE 1600000
#define HD 64
#define NL 3
#define NG 256

// m = h @ W   (W is [64][64] row-major: W[k*64+c])
__global__ __launch_bounds__(256) void k_lin(const float* __restrict__ h,
                                             const float* __restrict__ W,
                                             float* __restrict__ m) {
    __shared__ float Wl[HD * HD];
    for (int i = threadIdx.x; i < HD * HD; i += 256) Wl[i] = W[i];
    __syncthreads();
    int lane = threadIdx.x & 63, wid = threadIdx.x >> 6;
    int step = gridDim.x * 4;
    for (int n = blockIdx.x * 4 + wid; n < NN; n += step) {
        float hv = h[n * HD + lane];
        float acc = 0.f;
        #pragma unroll
        for (int k = 0; k < HD; ++k)
            acc = fmaf(__shfl(hv, k, 64), Wl[k * HD + lane], acc);
        m[n * HD + lane] = acc;
    }
}

// agg[dst] += m[src] over all edges; one wave per edge, lane = feature channel
__global__ __launch_bounds__(256) void k_scatter(const float* __restrict__ m,
                                                 const int* __restrict__ ei,
                                                 float* __restrict__ agg) {
    long long tid = (long long)blockIdx.x * 256 + threadIdx.x;
    long long stride = (long long)gridDim.x * 256;
    const long long total = (long long)NE * HD;
    for (long long i = tid; i < total; i += stride) {
        int e = (int)(i >> 6);
        int c = (int)(i & 63);
        int s = ei[e];
        int d = ei[NE + e];
        atomicAdd(&agg[d * HD + c], m[s * HD + c]);
    }
}

// gi = agg @ W_ih^T + b_ih   (W_ih is [192][64]; stage transposed [64][192] in LDS)
__global__ __launch_bounds__(256) void k_gi(const float* __restrict__ agg,
                                            const float* __restrict__ Wih,
                                            const float* __restrict__ bih,
                                            float* __restrict__ gi) {
    __shared__ float WT[HD * 192];
    for (int i = threadIdx.x; i < HD * 192; i += 256) {
        int k = i / 192, j = i % 192;
        WT[i] = Wih[j * HD + k];
    }
    __syncthreads();
    int lane = threadIdx.x & 63, wid = threadIdx.x >> 6;
    float b0 = bih[lane], b1 = bih[64 + lane], b2 = bih[128 + lane];
    int step = gridDim.x * 4;
    for (int n = blockIdx.x * 4 + wid; n < NN; n += step) {
        float av = agg[n * HD + lane];
        float a0 = b0, a1 = b1, a2 = b2;
        #pragma unroll
        for (int k = 0; k < HD; ++k) {
            float ak = __shfl(av, k, 64);
            a0 = fmaf(ak, WT[k * 192 + lane], a0);
            a1 = fmaf(ak, WT[k * 192 + 64 + lane], a1);
            a2 = fmaf(ak, WT[k * 192 + 128 + lane], a2);
        }
        gi[n * 192 + lane] = a0;
        gi[n * 192 + 64 + lane] = a1;
        gi[n * 192 + 128 + lane] = a2;
    }
}

// gh = h @ W_hh^T + b_hh fused with GRU pointwise combine; h updated in place.
__global__ __launch_bounds__(256) void k_gru(const float* __restrict__ gi,
                                             const float* __restrict__ Whh,
                                             const float* __restrict__ bhh,
                                             float* __restrict__ h) {
    __shared__ float WT[HD * 192];
    for (int i = threadIdx.x; i < HD * 192; i += 256) {
        int k = i / 192, j = i % 192;
        WT[i] = Whh[j * HD + k];
    }
    __syncthreads();
    int lane = threadIdx.x & 63, wid = threadIdx.x >> 6;
    float b0 = bhh[lane], b1 = bhh[64 + lane], b2 = bhh[128 + lane];
    int step = gridDim.x * 4;
    for (int n = blockIdx.x * 4 + wid; n < NN; n += step) {
        float hv = h[n * HD + lane];
        float g0 = b0, g1 = b1, g2 = b2;
        #pragma unroll
        for (int k = 0; k < HD; ++k) {
            float hk = __shfl(hv, k, 64);
            g0 = fmaf(hk, WT[k * 192 + lane], g0);
            g1 = fmaf(hk, WT[k * 192 + 64 + lane], g1);
            g2 = fmaf(hk, WT[k * 192 + 128 + lane], g2);
        }
        float ir = gi[n * 192 + lane];
        float iz = gi[n * 192 + 64 + lane];
        float inn = gi[n * 192 + 128 + lane];
        float r = 1.f / (1.f + expf(-(ir + g0)));
        float z = 1.f / (1.f + expf(-(iz + g1)));
        float nn = tanhf(inn + r * g2);
        h[n * HD + lane] = (1.f - z) * nn + z * hv;
    }
}

// batch is sorted: each wave owns a contiguous node range, flushes per-graph runs
__global__ __launch_bounds__(256) void k_pool(const float* __restrict__ h,
                                              const int* __restrict__ batch,
                                              float* __restrict__ out) {
    int gw = (int)((blockIdx.x * 256 + threadIdx.x) >> 6);
    int lane = threadIdx.x & 63;
    int nw = (gridDim.x * 256) >> 6;
    int per = (NN + nw - 1) / nw;
    int s = gw * per;
    int e = s + per; if (e > NN) e = NN;
    if (s >= NN) return;
    float acc = 0.f;
    int cur = batch[s];
    for (int n = s; n < e; ++n) {
        int b = batch[n];
        if (b != cur) {
            atomicAdd(&out[cur * HD + lane], acc);
            acc = 0.f; cur = b;
        }
        acc += h[n * HD + lane];
    }
    atomicAdd(&out[cur * HD + lane], acc);
}

extern "C" void kernel_launch(void* const* d_in, const int* in_sizes, int n_in,
                              void* d_out, int out_size, void* d_ws, size_t ws_size,
                              hipStream_t stream) {
    const float* x      = (const float*)d_in[0];
    const int*   ei     = (const int*)d_in[1];
    const int*   batch  = (const int*)d_in[2];
    const float* weight = (const float*)d_in[3];
    const float* Wih    = (const float*)d_in[4];
    const float* Whh    = (const float*)d_in[5];
    const float* bih    = (const float*)d_in[6];
    const float* bhh    = (const float*)d_in[7];
    float* out = (float*)d_out;

    char* ws = (char*)d_ws;
    const size_t szH = (size_t)NN * HD * sizeof(float);      // 25.6 MB
    float* H  = (float*)(ws);                                 // current h (in-place)
    float* M  = (float*)(ws + szH);                           // m
    float* AG = (float*)(ws + 2 * szH);                       // agg
    float* GI = (float*)(ws + 3 * szH);                       // gi [NN,192] 76.8 MB

    hipMemcpyAsync(H, x, szH, hipMemcpyDeviceToDevice, stream);

    for (int l = 0; l < NL; ++l) {
        k_lin<<<1024, 256, 0, stream>>>(H, weight + (size_t)l * HD * HD, M);
        hipMemsetAsync(AG, 0, szH, stream);
        k_scatter<<<2048, 256, 0, stream>>>(M, ei, AG);
        k_gi<<<1024, 256, 0, stream>>>(AG, Wih, bih, GI);
        k_gru<<<1024, 256, 0, stream>>>(GI, Whh, bhh, H);
    }

    hipMemsetAsync(out, 0, (size_t)NG * HD * sizeof(float), stream);
    k_pool<<<512, 256, 0, stream>>>(H, batch, out);
}